// Round 4
// baseline (4210.299 us; speedup 1.0000x reference)
//
#include <hip/hip_runtime.h>
#include <cstdint>
#include <cstddef>

#define NNODES 50000
#define NEDGES 800000
#define FIN    100
#define FOUT   200
#define FCAT   300
#define NSTEPS 8

typedef unsigned short ushort_t;
typedef __bf16 bf16x8 __attribute__((ext_vector_type(8)));
typedef float  floatx4 __attribute__((ext_vector_type(4)));

__device__ __forceinline__ float bf2f(ushort_t u) {
  union { unsigned u; float f; } c; c.u = ((unsigned)u) << 16; return c.f;
}
__device__ __forceinline__ ushort_t f2bf(float f) {
  union { float f; unsigned u; } c; c.f = f;
  unsigned r = c.u + 0x7FFFu + ((c.u >> 16) & 1u);
  return (ushort_t)(r >> 16);
}
// read external input element i: f32 flag chooses float32 vs bf16 interpretation
__device__ __forceinline__ float inval(const void* p, size_t i, int f32) {
  return f32 ? ((const float*)p)[i] : bf2f(((const ushort_t*)p)[i]);
}

// ---------------------------------------------------------------- dtype probe
// bf16 normal(0,1) data: even-indexed uint16s are real bf16 values, |v| < 512 always.
// f32 data: even-indexed uint16s are mantissa-low words (~uniform) -> ~47% have
// biased exponent >= 0x88 (|v|>=2^9) when decoded as bf16.
__global__ void probe_kernel(const void* xraw, int* flag) {
  const ushort_t* u = (const ushort_t*)xraw;
  int t = threadIdx.x;
  int bad = 0;
  for (int i = t; i < 2048; i += 64) {
    int e = (u[2 * i] >> 7) & 0xFF;
    if (e >= 0x88) bad++;
  }
  for (int off = 32; off; off >>= 1) bad += __shfl_down(bad, off);
  if (t == 0) *flag = (bad > 128) ? 1 : 0;
}

// ---------------------------------------------------------------- utility
__global__ void zero_kernel(int* p, int n) {
  int i = blockIdx.x * 256 + threadIdx.x;
  if (i < n) p[i] = 0;
}

__global__ void sentinel_kernel(ushort_t* out) {
  if (threadIdx.x == 0 && blockIdx.x == 0) {
    out[0] = f2bf(0.123f);   // diagnostic: ws_size too small
    out[1] = f2bf(0.877f);
  }
}

__global__ void hinit_kernel(const void* __restrict__ x, const int* __restrict__ dflag,
                             ushort_t* __restrict__ h) {
  const int f32 = *dflag;
  int i = blockIdx.x * 256 + threadIdx.x;
  if (i >= NNODES * FOUT) return;
  int n = i / FOUT, c = i % FOUT;
  h[i] = (c < FIN) ? f2bf(inval(x, (size_t)n * FIN + c, f32)) : (ushort_t)0;
}

__global__ void ccat_kernel(const ushort_t* __restrict__ h, const void* __restrict__ x,
                            const int* __restrict__ dflag, ushort_t* __restrict__ cc) {
  const int f32 = *dflag;
  int i = blockIdx.x * 256 + threadIdx.x;
  if (i >= NNODES * FCAT) return;
  int n = i / FCAT, c = i % FCAT;
  cc[i] = (c < FOUT) ? h[n * FOUT + c] : f2bf(inval(x, (size_t)n * FIN + (c - FOUT), f32));
}

// ---------------------------------------------------------------- CSR build
__global__ void hist_kernel(const int* __restrict__ dst, int* __restrict__ cnt) {
  int e = blockIdx.x * 256 + threadIdx.x;
  if (e < NEDGES) atomicAdd(&cnt[dst[e]], 1);
}

__global__ void scan_kernel(const int* __restrict__ cnt, int* __restrict__ row_ptr,
                            int* __restrict__ cursor) {
  __shared__ int part[1024];
  int t = threadIdx.x;
  const int per = (NNODES + 1023) / 1024;
  int st = t * per, en = st + per; if (en > NNODES) en = NNODES;
  if (st > NNODES) st = NNODES;
  int s = 0;
  for (int i = st; i < en; i++) s += cnt[i];
  part[t] = s;
  __syncthreads();
  for (int off = 1; off < 1024; off <<= 1) {
    int v = 0;
    if (t >= off) v = part[t - off];
    __syncthreads();
    part[t] += v;
    __syncthreads();
  }
  int run = (t == 0) ? 0 : part[t - 1];
  for (int i = st; i < en; i++) { row_ptr[i] = run; cursor[i] = run; run += cnt[i]; }
  if (t == 1023) row_ptr[NNODES] = run;
}

__global__ void fill_kernel(const int* __restrict__ srcv, const int* __restrict__ dstv,
                            int* __restrict__ cursor, int* __restrict__ csr_src) {
  int e = blockIdx.x * 256 + threadIdx.x;
  if (e >= NEDGES) return;
  int p = atomicAdd(&cursor[dstv[e]], 1);
  csr_src[p] = srcv[e];
}

// agg[n] = sum over in-edges of h[src]; writes A = [agg | h] row (400 wide, bf16)
__global__ __launch_bounds__(256) void gather_kernel(
    const int* __restrict__ row_ptr, const int* __restrict__ csr_src,
    const ushort_t* __restrict__ h, ushort_t* __restrict__ Ag) {
  int n = blockIdx.x;
  int c = threadIdx.x;
  int s0 = row_ptr[n], s1 = row_ptr[n + 1];
  if (c < FOUT) {
    float acc = 0.f;
    for (int i = s0; i < s1; i++) {
      int s = csr_src[i];
      acc += bf2f(h[(size_t)s * FOUT + c]);
    }
    Ag[(size_t)n * 400 + c] = f2bf(acc);
    Ag[(size_t)n * 400 + FOUT + c] = h[(size_t)n * FOUT + c];
  }
}

// ---------------------------------------------------------------- B^T builders
// Wp[l][k][j] = sum_i ggnn_w[l][k][i] * gru_wih[j][i]   ([8][200][600] fp32)
__global__ void wp_kernel(const void* __restrict__ gw, const void* __restrict__ wih,
                          const int* __restrict__ dflag, float* __restrict__ Wp) {
  const int f32 = *dflag;
  int i = blockIdx.x * 256 + threadIdx.x;
  if (i >= NSTEPS * FOUT * 600) return;
  int l = i / (FOUT * 600);
  int rem = i % (FOUT * 600);
  int k = rem / 600;
  int j = rem % 600;
  size_t abase = ((size_t)l * FOUT + k) * FOUT;
  size_t wbase = (size_t)j * FOUT;
  float s = 0.f;
  for (int q = 0; q < FOUT; q++) s += inval(gw, abase + q, f32) * inval(wih, wbase + q, f32);
  Wp[i] = s;
}

// Bt_gru: [8][832 rows n][416 k] bf16 (B^T, zero-padded k>=400)
// col groups: n = g*200+c : g0=r(sum), g1=z(sum), g2=ic(agg only), g3=hc(h only)
__global__ void btgru_kernel(const float* __restrict__ Wp, const void* __restrict__ whh,
                             const int* __restrict__ dflag, ushort_t* __restrict__ Bt) {
  const int f32 = *dflag;
  int i = blockIdx.x * 256 + threadIdx.x;
  if (i >= NSTEPS * 800 * 416) return;
  int l = i / (800 * 416);
  int rem = i % (800 * 416);
  int nn = rem / 416;
  int k = rem % 416;
  int g = nn / 200, c = nn % 200;
  float v = 0.f;
  if (k < 200) {
    const float* wrow = Wp + ((size_t)l * 200 + k) * 600;
    if (g == 0) v = wrow[c];
    else if (g == 1) v = wrow[200 + c];
    else if (g == 2) v = wrow[400 + c];
  } else if (k < 400) {
    int kh = k - 200;
    if (g == 0) v = inval(whh, (size_t)c * 200 + kh, f32);
    else if (g == 1) v = inval(whh, (size_t)(200 + c) * 200 + kh, f32);
    else if (g == 3) v = inval(whh, (size_t)(400 + c) * 200 + kh, f32);
  }
  Bt[((size_t)l * 832 + nn) * 416 + k] = f2bf(v);
}

// conv weight [O][C][KT] -> Bt[o][ktap*C + ci], zero pad to Kp
__global__ void btconv_kernel(const void* __restrict__ w, const int* __restrict__ dflag,
                              ushort_t* __restrict__ Bt, int C, int KT, int Kp, int total) {
  const int f32 = *dflag;
  int i = blockIdx.x * 256 + threadIdx.x;
  if (i >= total) return;
  int o = i / Kp, k = i % Kp;
  float v = 0.f;
  int K = C * KT;
  if (k < K) {
    int ktap = k / C; int ci = k % C;
    v = inval(w, ((size_t)o * C + ci) * KT + ktap, f32);
  }
  Bt[i] = f2bf(v);
}

// ---------------------------------------------------------------- GEMM (MFMA)
// C[M,N](+bias fp32) = A[M,K] (bf16 row-major, stride lda, rows may overlap) x B,
// B given as Bt[N][Kp] (B^T, row stride Kp, zero-padded past true K).
template <bool OUT_BF16>
__global__ __launch_bounds__(256) void gemm_bf16(
    const ushort_t* __restrict__ A, int lda, const ushort_t* __restrict__ Bt,
    void* __restrict__ Cv, int ldc, int M, int N, int Kp,
    const float* __restrict__ bias) {
  __shared__ ushort_t As[64 * 40];
  __shared__ ushort_t Bs[64 * 40];
  int tid = threadIdx.x;
  int m0 = blockIdx.x * 64;
  int n0 = blockIdx.y * 64;
  int lane = tid & 63;
  int quad = lane >> 4;
  int l15 = lane & 15;
  int w = tid >> 6;
  int wm = w & 1, wn = w >> 1;
  int srow = tid >> 2, sch = tid & 3;
  int arow = m0 + srow; if (arow >= M) arow = M - 1;   // clamped; stores guarded
  const ushort_t* gA = A + (size_t)arow * lda + sch * 8;
  const ushort_t* gB = Bt + (size_t)(n0 + srow) * Kp + sch * 8;
  ushort_t* dA = &As[srow * 40 + sch * 8];
  ushort_t* dB = &Bs[srow * 40 + sch * 8];

  floatx4 vzero = {0.f, 0.f, 0.f, 0.f};
  floatx4 acc[2][2];
  acc[0][0] = vzero; acc[0][1] = vzero; acc[1][0] = vzero; acc[1][1] = vzero;

  for (int k0 = 0; k0 < Kp; k0 += 32) {
    int2 a0v = *(const int2*)(gA + k0);
    int2 a1v = *(const int2*)(gA + k0 + 4);
    int2 b0v = *(const int2*)(gB + k0);
    int2 b1v = *(const int2*)(gB + k0 + 4);
    ((int2*)dA)[0] = a0v; ((int2*)dA)[1] = a1v;
    ((int2*)dB)[0] = b0v; ((int2*)dB)[1] = b1v;
    __syncthreads();
    bf16x8 a0 = *(const bf16x8*)&As[(wm * 32 + l15) * 40 + quad * 8];
    bf16x8 a1 = *(const bf16x8*)&As[(wm * 32 + 16 + l15) * 40 + quad * 8];
    bf16x8 b0 = *(const bf16x8*)&Bs[(wn * 32 + l15) * 40 + quad * 8];
    bf16x8 b1 = *(const bf16x8*)&Bs[(wn * 32 + 16 + l15) * 40 + quad * 8];
    acc[0][0] = __builtin_amdgcn_mfma_f32_16x16x32_bf16(a0, b0, acc[0][0], 0, 0, 0);
    acc[0][1] = __builtin_amdgcn_mfma_f32_16x16x32_bf16(a0, b1, acc[0][1], 0, 0, 0);
    acc[1][0] = __builtin_amdgcn_mfma_f32_16x16x32_bf16(a1, b0, acc[1][0], 0, 0, 0);
    acc[1][1] = __builtin_amdgcn_mfma_f32_16x16x32_bf16(a1, b1, acc[1][1], 0, 0, 0);
    __syncthreads();
  }
  #pragma unroll
  for (int tm = 0; tm < 2; tm++)
    #pragma unroll
    for (int tn = 0; tn < 2; tn++)
      #pragma unroll
      for (int r = 0; r < 4; r++) {
        int row = m0 + wm * 32 + tm * 16 + quad * 4 + r;
        int col = n0 + wn * 32 + tn * 16 + l15;
        if (row < M && col < N) {
          float v = acc[tm][tn][r];
          if (bias) v += bias[col];
          if (OUT_BF16) ((ushort_t*)Cv)[(size_t)row * ldc + col] = f2bf(v);
          else          ((float*)Cv)[(size_t)row * ldc + col] = v;
        }
      }
}

// bias staging: external (dtype-flagged) -> fp32 scratch
__global__ void bias_kernel(const void* __restrict__ b, const int* __restrict__ dflag,
                            float* __restrict__ out, int n) {
  const int f32 = *dflag;
  int i = blockIdx.x * 256 + threadIdx.x;
  if (i < n) out[i] = inval(b, i, f32);
}

// ---------------------------------------------------------------- GRU elementwise
__global__ void gru_kernel(const ushort_t* __restrict__ G, const void* __restrict__ bih,
                           const void* __restrict__ bhh, const int* __restrict__ dflag,
                           ushort_t* __restrict__ h) {
  const int f32 = *dflag;
  int i = blockIdx.x * 256 + threadIdx.x;
  if (i >= NNODES * FOUT) return;
  int n = i / FOUT, c = i % FOUT;
  const ushort_t* g = G + (size_t)n * 800;
  float rr = bf2f(g[c])       + inval(bih, c, f32)       + inval(bhh, c, f32);
  float zz = bf2f(g[200 + c]) + inval(bih, 200 + c, f32) + inval(bhh, 200 + c, f32);
  float ic = bf2f(g[400 + c]) + inval(bih, 400 + c, f32);
  float hc = bf2f(g[600 + c]) + inval(bhh, 400 + c, f32);
  float r = 1.f / (1.f + expf(-rr));
  float z = 1.f / (1.f + expf(-zz));
  float nn = tanhf(ic + r * hc);
  float ho = bf2f(h[i]);
  h[i] = f2bf((1.f - z) * nn + z * ho);
}

// ---------------------------------------------------------------- BN stats + pool
__global__ void stats_kernel(const float* __restrict__ X, int Lrows, int C,
                             float* __restrict__ sums, float* __restrict__ sumsq) {
  int r0 = blockIdx.x * 64;
  int rend = r0 + 64; if (rend > Lrows) rend = Lrows;
  for (int c = threadIdx.x; c < C; c += 256) {
    float s = 0.f, ss = 0.f;
    for (int r = r0; r < rend; r++) {
      float v = X[(size_t)r * C + c];
      s += v; ss += v * v;
    }
    atomicAdd(&sums[c], s);
    atomicAdd(&sumsq[c], ss);
  }
}

__global__ void bnpool_kernel(const float* __restrict__ X, int Lin, int C, int kk, int ss,
                              int Lp, const float* __restrict__ sums,
                              const float* __restrict__ sumsq,
                              const void* __restrict__ g, const void* __restrict__ b,
                              const int* __restrict__ dflag, ushort_t* __restrict__ out) {
  const int f32 = *dflag;
  int i = blockIdx.x * 256 + threadIdx.x;
  if (i >= Lp * C) return;
  int p = i / C, c = i % C;
  float inv = 1.f / (float)Lin;
  float mu = sums[c] * inv;
  float var = sumsq[c] * inv - mu * mu; if (var < 0.f) var = 0.f;
  float scale = inval(g, c, f32) * rsqrtf(var + 1e-5f);
  float shift = inval(b, c, f32) - mu * scale;
  float m = -1e30f;
  int base = p * ss;
  for (int r = 0; r < kk; r++) {
    float v = X[(size_t)(base + r) * C + c] * scale + shift;
    if (v > m) m = v;
  }
  if (m < 0.f) m = 0.f;
  out[(size_t)p * C + c] = f2bf(m);
}

// ---------------------------------------------------------------- head
__global__ void final_kernel(const ushort_t* __restrict__ Y2, const ushort_t* __restrict__ Z2,
                             const void* __restrict__ wy, const void* __restrict__ by,
                             const void* __restrict__ wz, const void* __restrict__ bz,
                             const int* __restrict__ dflag, float* __restrict__ accum) {
  const int f32 = *dflag;
  int row = blockIdx.x * 4 + (threadIdx.x >> 6);
  int lane = threadIdx.x & 63;
  if (row >= 12497) return;
  float y0 = 0.f, y1 = 0.f, z0 = 0.f, z1 = 0.f;
  for (int c = lane; c < 200; c += 64) {
    float v = bf2f(Y2[(size_t)row * 200 + c]);
    y0 += v * inval(wy, c, f32);
    y1 += v * inval(wy, 200 + c, f32);
  }
  for (int c = lane; c < 300; c += 64) {
    float v = bf2f(Z2[(size_t)row * 300 + c]);
    z0 += v * inval(wz, c, f32);
    z1 += v * inval(wz, 300 + c, f32);
  }
  for (int off = 32; off > 0; off >>= 1) {
    y0 += __shfl_down(y0, off);
    y1 += __shfl_down(y1, off);
    z0 += __shfl_down(z0, off);
    z1 += __shfl_down(z1, off);
  }
  if (lane == 0) {
    float p0 = (y0 + inval(by, 0, f32)) * (z0 + inval(bz, 0, f32));
    float p1 = (y1 + inval(by, 1, f32)) * (z1 + inval(bz, 1, f32));
    atomicAdd(&accum[0], p0);
    atomicAdd(&accum[1], p1);
  }
}

__global__ void finalize_kernel(const float* __restrict__ accum, const int* __restrict__ dflag,
                                void* __restrict__ out) {
  const int f32 = *dflag;
  if (threadIdx.x == 0 && blockIdx.x == 0) {
    float a0 = accum[0] / 12497.f;
    float a1 = accum[1] / 12497.f;
    float mx = fmaxf(a0, a1);
    float e0 = expf(a0 - mx), e1 = expf(a1 - mx);
    float s = e0 + e1;
    if (f32) {
      ((float*)out)[0] = e0 / s;
      ((float*)out)[1] = e1 / s;
    } else {
      ((ushort_t*)out)[0] = f2bf(e0 / s);
      ((ushort_t*)out)[1] = f2bf(e1 / s);
    }
  }
}

// ---------------------------------------------------------------- launch
extern "C" void kernel_launch(void* const* d_in, const int* in_sizes, int n_in,
                              void* d_out, int out_size, void* d_ws, size_t ws_size,
                              hipStream_t stream) {
  const void* x        = d_in[0];
  const int*  edge     = (const int*)d_in[1];
  const void* ggnn_w   = d_in[2];
  const void* gru_wih  = d_in[3];
  const void* gru_whh  = d_in[4];
  const void* gru_bih  = d_in[5];
  const void* gru_bhh  = d_in[6];
  const void* conv1_w  = d_in[7];
  const void* conv1_b  = d_in[8];
  const void* conv2_w  = d_in[9];
  const void* conv2_b  = d_in[10];
  const void* conv1c_w = d_in[11];
  const void* conv1c_b = d_in[12];
  const void* conv2c_w = d_in[13];
  const void* conv2c_b = d_in[14];
  const void* bn_g     = d_in[15];
  const void* bn_b     = d_in[16];
  const void* bnc_g    = d_in[17];
  const void* bnc_b    = d_in[18];
  const void* mlpy_w   = d_in[19];
  const void* mlpy_b   = d_in[20];
  const void* mlpz_w   = d_in[21];
  const void* mlpz_b   = d_in[22];
  const int* srcv = edge;
  const int* dstv = edge + NEDGES;

  // ---- workspace layout (aliased; total ~173 MB) ----
  char* p = (char*)d_ws;
  auto alloc = [&](size_t bytes) -> char* {
    char* r = p; p += (bytes + 255) & ~(size_t)255; return r;
  };
  ushort_t* h    = (ushort_t*)alloc(((size_t)NNODES * FOUT + 64) * 2);     // 20 MB
  ushort_t* Ag   = (ushort_t*)alloc(((size_t)NNODES * 400 + 64) * 2);     // 40 MB (cc aliases)
  ushort_t* cc   = Ag;  // cc[N,300] built AFTER GRU loop, Ag then dead
  char*     R    = alloc((size_t)98 * 1000 * 1000);                        // 98 MB arena
  ushort_t* G    = (ushort_t*)R;                  // [N,800] bf16 GRU gates (GRU phase only)
  float*    C1   = (float*)R;                     // 40 MB  (conv phase, sequential)
  float*    C2   = (float*)R;                     // 20 MB
  float*    C1c  = (float*)R;                     // 60 MB
  float*    C2c  = (float*)R;                     // 30 MB
  ushort_t* pooled1 = (ushort_t*)(R + 60000000);  // 10 MB, live while C2 written
  ushort_t* pooledc = (ushort_t*)(R + 70000000);  // 15 MB, live while C2c written
  ushort_t* Y2      = (ushort_t*)(R + 85000000);  //  5 MB
  ushort_t* Z2      = (ushort_t*)(R + 90000000);  //  7.5 MB (ends 97.5 MB)
  ushort_t* BtG  = (ushort_t*)alloc((size_t)8 * 832 * 416 * 2);
  ushort_t* Bt1  = (ushort_t*)alloc((size_t)256 * 800 * 2);
  ushort_t* Bt2  = (ushort_t*)alloc((size_t)256 * 416 * 2);
  ushort_t* Bt1c = (ushort_t*)alloc((size_t)320 * 1216 * 2);
  ushort_t* Bt2c = (ushort_t*)alloc((size_t)320 * 608 * 2);
  float*    Wp   = (float*)alloc((size_t)8 * 200 * 600 * 4);
  int*   csr_src = (int*)alloc((size_t)NEDGES * 4);
  int*   row_ptr = (int*)alloc((size_t)(NNODES + 1) * 4);
  int*   cursor  = (int*)alloc((size_t)NNODES * 4);
  int*   cnt     = (int*)alloc((size_t)NNODES * 4);
  float* sb      = (float*)alloc((size_t)3300 * 4);
  float *s1 = sb, *ss1 = sb + 200, *s2 = sb + 400, *ss2 = sb + 600;
  float *sc1 = sb + 800, *ssc1 = sb + 1100, *sc2 = sb + 1400, *ssc2 = sb + 1700;
  float* accum = sb + 2000;
  int*   dflag = (int*)(sb + 2002);
  float* b1f   = sb + 2010;   // fp32 bias staging: 200
  float* b2f   = sb + 2210;   // 200
  float* b1cf  = sb + 2410;   // 300
  float* b2cf  = sb + 2710;   // 300 (ends 3010)

  size_t required = (size_t)(p - (char*)d_ws);
  if (required > ws_size) {
    sentinel_kernel<<<1, 64, 0, stream>>>((ushort_t*)d_out);
    return;
  }

  probe_kernel<<<1, 64, 0, stream>>>(x, dflag);
  zero_kernel<<<(NNODES + 255) / 256, 256, 0, stream>>>(cnt, NNODES);
  zero_kernel<<<(2002 + 255) / 256, 256, 0, stream>>>((int*)sb, 2002);
  hinit_kernel<<<(NNODES * FOUT + 255) / 256, 256, 0, stream>>>(x, dflag, h);
  wp_kernel<<<(NSTEPS * FOUT * 600 + 255) / 256, 256, 0, stream>>>(ggnn_w, gru_wih, dflag, Wp);
  btgru_kernel<<<(NSTEPS * 800 * 416 + 255) / 256, 256, 0, stream>>>(Wp, gru_whh, dflag, BtG);
  btconv_kernel<<<(200 * 800 + 255) / 256, 256, 0, stream>>>(conv1_w, dflag, Bt1, 200, 4, 800, 200 * 800);
  btconv_kernel<<<(200 * 416 + 255) / 256, 256, 0, stream>>>(conv2_w, dflag, Bt2, 200, 2, 416, 200 * 416);
  btconv_kernel<<<(300 * 1216 + 255) / 256, 256, 0, stream>>>(conv1c_w, dflag, Bt1c, 300, 4, 1216, 300 * 1216);
  btconv_kernel<<<(300 * 608 + 255) / 256, 256, 0, stream>>>(conv2c_w, dflag, Bt2c, 300, 2, 608, 300 * 608);
  bias_kernel<<<1, 256, 0, stream>>>(conv1_b, dflag, b1f, 200);
  bias_kernel<<<1, 256, 0, stream>>>(conv2_b, dflag, b2f, 200);
  bias_kernel<<<2, 256, 0, stream>>>(conv1c_b, dflag, b1cf, 300);
  bias_kernel<<<2, 256, 0, stream>>>(conv2c_b, dflag, b2cf, 300);

  hist_kernel<<<(NEDGES + 255) / 256, 256, 0, stream>>>(dstv, cnt);
  scan_kernel<<<1, 1024, 0, stream>>>(cnt, row_ptr, cursor);
  fill_kernel<<<(NEDGES + 255) / 256, 256, 0, stream>>>(srcv, dstv, cursor, csr_src);

  for (int l = 0; l < NSTEPS; l++) {
    gather_kernel<<<NNODES, 256, 0, stream>>>(row_ptr, csr_src, h, Ag);
    gemm_bf16<true><<<dim3(782, 13), 256, 0, stream>>>(Ag, 400, BtG + (size_t)l * 832 * 416,
                                                       G, 800, NNODES, 800, 416, nullptr);
    gru_kernel<<<(NNODES * FOUT + 255) / 256, 256, 0, stream>>>(G, gru_bih, gru_bhh, dflag, h);
  }
  ccat_kernel<<<(NNODES * FCAT + 255) / 256, 256, 0, stream>>>(h, x, dflag, cc);

  // branch y
  gemm_bf16<false><<<dim3(782, 4), 256, 0, stream>>>(h, 200, Bt1, C1, 200, 49997, 200, 800, b1f);
  stats_kernel<<<(49997 + 63) / 64, 256, 0, stream>>>(C1, 49997, 200, s1, ss1);
  bnpool_kernel<<<(24997 * 200 + 255) / 256, 256, 0, stream>>>(C1, 49997, 200, 4, 2, 24997,
                                                               s1, ss1, bn_g, bn_b, dflag, pooled1);
  gemm_bf16<false><<<dim3(391, 4), 256, 0, stream>>>(pooled1, 200, Bt2, C2, 200, 24996, 200, 416, b2f);
  stats_kernel<<<(24996 + 63) / 64, 256, 0, stream>>>(C2, 24996, 200, s2, ss2);
  bnpool_kernel<<<(12497 * 200 + 255) / 256, 256, 0, stream>>>(C2, 24996, 200, 3, 2, 12497,
                                                               s2, ss2, bn_g, bn_b, dflag, Y2);
  // branch z
  gemm_bf16<false><<<dim3(782, 5), 256, 0, stream>>>(cc, 300, Bt1c, C1c, 300, 49997, 300, 1216, b1cf);
  stats_kernel<<<(49997 + 63) / 64, 256, 0, stream>>>(C1c, 49997, 300, sc1, ssc1);
  bnpool_kernel<<<(24997 * 300 + 255) / 256, 256, 0, stream>>>(C1c, 49997, 300, 4, 2, 24997,
                                                               sc1, ssc1, bnc_g, bnc_b, dflag, pooledc);
  gemm_bf16<false><<<dim3(391, 5), 256, 0, stream>>>(pooledc, 300, Bt2c, C2c, 300, 24996, 300, 608, b2cf);
  stats_kernel<<<(24996 + 63) / 64, 256, 0, stream>>>(C2c, 24996, 300, sc2, ssc2);
  bnpool_kernel<<<(12497 * 300 + 255) / 256, 256, 0, stream>>>(C2c, 24996, 300, 3, 2, 12497,
                                                               sc2, ssc2, bnc_g, bnc_b, dflag, Z2);

  final_kernel<<<(12497 + 3) / 4, 256, 0, stream>>>(Y2, Z2, mlpy_w, mlpy_b, mlpz_w, mlpz_b, dflag, accum);
  finalize_kernel<<<1, 64, 0, stream>>>(accum, dflag, d_out);
}

// Round 5
// 2448.258 us; speedup vs baseline: 1.7197x; 1.7197x over previous
//
#include <hip/hip_runtime.h>
#include <cstdint>
#include <cstddef>

#define NNODES 50000
#define NEDGES 800000
#define FIN    100
#define FOUT   200
#define FCAT   300
#define NSTEPS 8

typedef unsigned short ushort_t;
typedef __bf16 bf16x8 __attribute__((ext_vector_type(8)));
typedef float  floatx4 __attribute__((ext_vector_type(4)));

__device__ __forceinline__ float bf2f(ushort_t u) {
  union { unsigned u; float f; } c; c.u = ((unsigned)u) << 16; return c.f;
}
__device__ __forceinline__ ushort_t f2bf(float f) {
  union { float f; unsigned u; } c; c.f = f;
  unsigned r = c.u + 0x7FFFu + ((c.u >> 16) & 1u);
  return (ushort_t)(r >> 16);
}
// read external input element i: f32 flag chooses float32 vs bf16 interpretation
__device__ __forceinline__ float inval(const void* p, size_t i, int f32) {
  return f32 ? ((const float*)p)[i] : bf2f(((const ushort_t*)p)[i]);
}

// ---------------------------------------------------------------- dtype probe
__global__ void probe_kernel(const void* xraw, int* flag) {
  const ushort_t* u = (const ushort_t*)xraw;
  int t = threadIdx.x;
  int bad = 0;
  for (int i = t; i < 2048; i += 64) {
    int e = (u[2 * i] >> 7) & 0xFF;
    if (e >= 0x88) bad++;
  }
  for (int off = 32; off; off >>= 1) bad += __shfl_down(bad, off);
  if (t == 0) *flag = (bad > 128) ? 1 : 0;
}

// ---------------------------------------------------------------- utility
__global__ void zero_kernel(int* p, int n) {
  int i = blockIdx.x * 256 + threadIdx.x;
  if (i < n) p[i] = 0;
}

__global__ void sentinel_kernel(ushort_t* out) {
  if (threadIdx.x == 0 && blockIdx.x == 0) {
    out[0] = f2bf(0.123f);   // diagnostic: ws_size too small
    out[1] = f2bf(0.877f);
  }
}

__global__ void hinit_kernel(const void* __restrict__ x, const int* __restrict__ dflag,
                             ushort_t* __restrict__ h) {
  const int f32 = *dflag;
  int i = blockIdx.x * 256 + threadIdx.x;
  if (i >= NNODES * FOUT) return;
  int n = i / FOUT, c = i % FOUT;
  h[i] = (c < FIN) ? f2bf(inval(x, (size_t)n * FIN + c, f32)) : (ushort_t)0;
}

__global__ void ccat_kernel(const ushort_t* __restrict__ h, const void* __restrict__ x,
                            const int* __restrict__ dflag, ushort_t* __restrict__ cc) {
  const int f32 = *dflag;
  int i = blockIdx.x * 256 + threadIdx.x;
  if (i >= NNODES * FCAT) return;
  int n = i / FCAT, c = i % FCAT;
  cc[i] = (c < FOUT) ? h[n * FOUT + c] : f2bf(inval(x, (size_t)n * FIN + (c - FOUT), f32));
}

// ---------------------------------------------------------------- CSR build
__global__ void hist_kernel(const int* __restrict__ dst, int* __restrict__ cnt) {
  int e = blockIdx.x * 256 + threadIdx.x;
  if (e < NEDGES) atomicAdd(&cnt[dst[e]], 1);
}

__global__ void scan_kernel(const int* __restrict__ cnt, int* __restrict__ row_ptr,
                            int* __restrict__ cursor) {
  __shared__ int part[1024];
  int t = threadIdx.x;
  const int per = (NNODES + 1023) / 1024;
  int st = t * per, en = st + per; if (en > NNODES) en = NNODES;
  if (st > NNODES) st = NNODES;
  int s = 0;
  for (int i = st; i < en; i++) s += cnt[i];
  part[t] = s;
  __syncthreads();
  for (int off = 1; off < 1024; off <<= 1) {
    int v = 0;
    if (t >= off) v = part[t - off];
    __syncthreads();
    part[t] += v;
    __syncthreads();
  }
  int run = (t == 0) ? 0 : part[t - 1];
  for (int i = st; i < en; i++) { row_ptr[i] = run; cursor[i] = run; run += cnt[i]; }
  if (t == 1023) row_ptr[NNODES] = run;
}

__global__ void fill_kernel(const int* __restrict__ srcv, const int* __restrict__ dstv,
                            int* __restrict__ cursor, int* __restrict__ csr_src) {
  int e = blockIdx.x * 256 + threadIdx.x;
  if (e >= NEDGES) return;
  int p = atomicAdd(&cursor[dstv[e]], 1);
  csr_src[p] = srcv[e];
}

// agg[n] = sum over in-edges of h[src]; writes A = [agg | h] row (400 wide, bf16)
// wave per node, lane covers 4 channels (ushort4), 2-edge unroll
__global__ __launch_bounds__(256) void gather_kernel(
    const int* __restrict__ row_ptr, const int* __restrict__ csr_src,
    const ushort_t* __restrict__ h, ushort_t* __restrict__ Ag) {
  int g = threadIdx.x >> 6;
  int lane = threadIdx.x & 63;
  int n = blockIdx.x * 4 + g;
  if (n >= NNODES) return;                 // whole wave exits together (no barriers below)
  if (lane >= 50) return;
  int s0 = row_ptr[n], s1 = row_ptr[n + 1];
  float a0 = 0.f, a1 = 0.f, a2 = 0.f, a3 = 0.f;
  int i = s0;
  for (; i + 1 < s1; i += 2) {
    int sa = csr_src[i], sb = csr_src[i + 1];
    ushort4 va = *(const ushort4*)&h[(size_t)sa * FOUT + lane * 4];
    ushort4 vb = *(const ushort4*)&h[(size_t)sb * FOUT + lane * 4];
    a0 += bf2f(va.x) + bf2f(vb.x);
    a1 += bf2f(va.y) + bf2f(vb.y);
    a2 += bf2f(va.z) + bf2f(vb.z);
    a3 += bf2f(va.w) + bf2f(vb.w);
  }
  if (i < s1) {
    int sa = csr_src[i];
    ushort4 va = *(const ushort4*)&h[(size_t)sa * FOUT + lane * 4];
    a0 += bf2f(va.x); a1 += bf2f(va.y); a2 += bf2f(va.z); a3 += bf2f(va.w);
  }
  ushort4 o;
  o.x = f2bf(a0); o.y = f2bf(a1); o.z = f2bf(a2); o.w = f2bf(a3);
  *(ushort4*)&Ag[(size_t)n * 400 + lane * 4] = o;
  *(ushort4*)&Ag[(size_t)n * 400 + FOUT + lane * 4] =
      *(const ushort4*)&h[(size_t)n * FOUT + lane * 4];
}

// ---------------------------------------------------------------- padded bf16 copies
// dst[r*Kp + k] = (r<rowsValid && k<K) ? src[r*K+k] : 0   (total = rowsPad*Kp)
__global__ void pada_kernel(const void* __restrict__ src, const int* __restrict__ dflag,
                            ushort_t* __restrict__ dst, int K, int Kp, int rowsValid,
                            int total) {
  const int f32 = *dflag;
  int i = blockIdx.x * 256 + threadIdx.x;
  if (i >= total) return;
  int r = i / Kp, k = i % Kp;
  float v = (r < rowsValid && k < K) ? inval(src, (size_t)r * K + k, f32) : 0.f;
  dst[i] = f2bf(v);
}

// Bt_gru: [8][896 rows n][416 k] bf16 (B^T, zero-padded rows>=800, k>=400)
// col groups: n = g*200+c : g0=r(sum), g1=z(sum), g2=ic(agg only), g3=hc(h only)
__global__ void btgru_kernel(const float* __restrict__ Wp, const void* __restrict__ whh,
                             const int* __restrict__ dflag, ushort_t* __restrict__ Bt) {
  const int f32 = *dflag;
  int i = blockIdx.x * 256 + threadIdx.x;
  if (i >= NSTEPS * 896 * 416) return;
  int l = i / (896 * 416);
  int rem = i % (896 * 416);
  int nn = rem / 416;
  int k = rem % 416;
  int g = nn / 200, c = nn % 200;
  float v = 0.f;
  if (k < 200) {
    const float* wrow = Wp + ((size_t)l * 200 + k) * 600;
    if (g == 0) v = wrow[c];
    else if (g == 1) v = wrow[200 + c];
    else if (g == 2) v = wrow[400 + c];
  } else if (k < 400) {
    int kh = k - 200;
    if (g == 0) v = inval(whh, (size_t)c * 200 + kh, f32);
    else if (g == 1) v = inval(whh, (size_t)(200 + c) * 200 + kh, f32);
    else if (g == 3) v = inval(whh, (size_t)(400 + c) * 200 + kh, f32);
  }
  Bt[((size_t)l * 896 + nn) * 416 + k] = f2bf(v);
}

// conv weight [O][C][KT] -> Bt[o][ktap*C + ci], zero pad to Kp cols and Opad rows
__global__ void btconv_kernel(const void* __restrict__ w, const int* __restrict__ dflag,
                              ushort_t* __restrict__ Bt, int C, int KT, int Kp,
                              int O, int total) {
  const int f32 = *dflag;
  int i = blockIdx.x * 256 + threadIdx.x;
  if (i >= total) return;
  int o = i / Kp, k = i % Kp;
  float v = 0.f;
  int K = C * KT;
  if (k < K && o < O) {
    int ktap = k / C; int ci = k % C;
    v = inval(w, ((size_t)o * C + ci) * KT + ktap, f32);
  }
  Bt[i] = f2bf(v);
}

// ---------------------------------------------------------------- GEMM (MFMA, 128x128 tile)
// C[M,N](+bias fp32) = A[M,K] (bf16 row-major, stride lda, rows may overlap) x B,
// B given as Bt[N][Kp] (B^T, row stride Kp); Bt must have >= gridDim.y*128 rows,
// zero-padded past true K/N. A rows clamped at M-1 (stores guarded).
template <bool OUT_BF16>
__global__ __launch_bounds__(256) void gemm128(
    const ushort_t* __restrict__ A, int lda, const ushort_t* __restrict__ Bt,
    void* __restrict__ Cv, int ldc, int M, int N, int Kp,
    const float* __restrict__ bias) {
  __shared__ alignas(16) ushort_t As[128 * 32];
  __shared__ alignas(16) ushort_t Bs[128 * 32];
  const int tid = threadIdx.x;
  const int m0 = blockIdx.x * 128;
  const int n0 = blockIdx.y * 128;
  const int lane = tid & 63;
  const int wv = tid >> 6;
  const int wm = wv & 1;
  const int wn = wv >> 1;
  const int quad = lane >> 4;
  const int l15 = lane & 15;

  floatx4 acc[4][4];
  #pragma unroll
  for (int a = 0; a < 4; a++)
    #pragma unroll
    for (int b = 0; b < 4; b++)
      acc[a][b] = (floatx4){0.f, 0.f, 0.f, 0.f};

  for (int k0 = 0; k0 < Kp; k0 += 32) {
    #pragma unroll
    for (int j = 0; j < 2; j++) {
      int cid = tid + 256 * j;          // 16B chunk id, 0..511
      int r = cid >> 2;                 // tile row 0..127
      int c8 = (cid & 3) * 8;           // ushort offset within 32-col row
      int ar = m0 + r; if (ar >= M) ar = M - 1;
      const ushort_t* ga = A + (size_t)ar * lda + k0 + c8;
      int2 x0 = *(const int2*)ga;
      int2 x1 = *(const int2*)(ga + 4);
      int4 bv = *(const int4*)(Bt + (size_t)(n0 + r) * Kp + k0 + c8);
      int4 av; av.x = x0.x; av.y = x0.y; av.z = x1.x; av.w = x1.y;
      *(int4*)&As[cid * 8] = av;
      *(int4*)&Bs[cid * 8] = bv;
    }
    __syncthreads();
    bf16x8 af[4], bfr[4];
    #pragma unroll
    for (int t = 0; t < 4; t++) {
      af[t]  = *(const bf16x8*)&As[(wm * 64 + t * 16 + l15) * 32 + quad * 8];
      bfr[t] = *(const bf16x8*)&Bs[(wn * 64 + t * 16 + l15) * 32 + quad * 8];
    }
    #pragma unroll
    for (int tm = 0; tm < 4; tm++)
      #pragma unroll
      for (int tn = 0; tn < 4; tn++)
        acc[tm][tn] = __builtin_amdgcn_mfma_f32_16x16x32_bf16(af[tm], bfr[tn], acc[tm][tn], 0, 0, 0);
    __syncthreads();
  }

  #pragma unroll
  for (int tm = 0; tm < 4; tm++) {
    int row = m0 + wm * 64 + tm * 16 + quad * 4;
    #pragma unroll
    for (int tn = 0; tn < 4; tn++) {
      int col = n0 + wn * 64 + tn * 16 + l15;
      if (col < N) {
        float bb = bias ? bias[col] : 0.f;
        #pragma unroll
        for (int r = 0; r < 4; r++) {
          if (row + r < M) {
            float v = acc[tm][tn][r] + bb;
            if (OUT_BF16) ((ushort_t*)Cv)[(size_t)(row + r) * ldc + col] = f2bf(v);
            else          ((float*)Cv)[(size_t)(row + r) * ldc + col] = v;
          }
        }
      }
    }
  }
}

// bias staging: external (dtype-flagged) -> fp32 scratch
__global__ void bias_kernel(const void* __restrict__ b, const int* __restrict__ dflag,
                            float* __restrict__ out, int n) {
  const int f32 = *dflag;
  int i = blockIdx.x * 256 + threadIdx.x;
  if (i < n) out[i] = inval(b, i, f32);
}

// ---------------------------------------------------------------- GRU elementwise
__global__ void gru_kernel(const ushort_t* __restrict__ G, const void* __restrict__ bih,
                           const void* __restrict__ bhh, const int* __restrict__ dflag,
                           ushort_t* __restrict__ h) {
  const int f32 = *dflag;
  int i = blockIdx.x * 256 + threadIdx.x;
  if (i >= NNODES * FOUT) return;
  int n = i / FOUT, c = i % FOUT;
  const ushort_t* g = G + (size_t)n * 800;
  float rr = bf2f(g[c])       + inval(bih, c, f32)       + inval(bhh, c, f32);
  float zz = bf2f(g[200 + c]) + inval(bih, 200 + c, f32) + inval(bhh, 200 + c, f32);
  float ic = bf2f(g[400 + c]) + inval(bih, 400 + c, f32);
  float hc = bf2f(g[600 + c]) + inval(bhh, 400 + c, f32);
  float r = 1.f / (1.f + expf(-rr));
  float z = 1.f / (1.f + expf(-zz));
  float nn = tanhf(ic + r * hc);
  float ho = bf2f(h[i]);
  h[i] = f2bf((1.f - z) * nn + z * ho);
}

// ---------------------------------------------------------------- BN stats + pool
__global__ void stats_kernel(const float* __restrict__ X, int Lrows, int C,
                             float* __restrict__ sums, float* __restrict__ sumsq) {
  int r0 = blockIdx.x * 64;
  int rend = r0 + 64; if (rend > Lrows) rend = Lrows;
  for (int c = threadIdx.x; c < C; c += 256) {
    float s = 0.f, ss = 0.f;
    for (int r = r0; r < rend; r++) {
      float v = X[(size_t)r * C + c];
      s += v; ss += v * v;
    }
    atomicAdd(&sums[c], s);
    atomicAdd(&sumsq[c], ss);
  }
}

__global__ void bnpool_kernel(const float* __restrict__ X, int Lin, int C, int kk, int ss,
                              int Lp, const float* __restrict__ sums,
                              const float* __restrict__ sumsq,
                              const void* __restrict__ g, const void* __restrict__ b,
                              const int* __restrict__ dflag, ushort_t* __restrict__ out) {
  const int f32 = *dflag;
  int i = blockIdx.x * 256 + threadIdx.x;
  if (i >= Lp * C) return;
  int p = i / C, c = i % C;
  float inv = 1.f / (float)Lin;
  float mu = sums[c] * inv;
  float var = sumsq[c] * inv - mu * mu; if (var < 0.f) var = 0.f;
  float scale = inval(g, c, f32) * rsqrtf(var + 1e-5f);
  float shift = inval(b, c, f32) - mu * scale;
  float m = -1e30f;
  int base = p * ss;
  for (int r = 0; r < kk; r++) {
    float v = X[(size_t)(base + r) * C + c] * scale + shift;
    if (v > m) m = v;
  }
  if (m < 0.f) m = 0.f;
  out[(size_t)p * C + c] = f2bf(m);
}

// ---------------------------------------------------------------- head (atomic-free)
__global__ __launch_bounds__(256) void final_kernel(
    const ushort_t* __restrict__ Y2, const ushort_t* __restrict__ Z2,
    const void* __restrict__ wy, const void* __restrict__ by,
    const void* __restrict__ wz, const void* __restrict__ bz,
    const int* __restrict__ dflag, float* __restrict__ pacc) {
  const int f32 = *dflag;
  __shared__ float bl[8];
  int g = threadIdx.x >> 6;
  int lane = threadIdx.x & 63;
  int row = blockIdx.x * 4 + g;
  float y0 = 0.f, y1 = 0.f, z0 = 0.f, z1 = 0.f;
  if (row < 12497) {
    for (int c = lane; c < 200; c += 64) {
      float v = bf2f(Y2[(size_t)row * 200 + c]);
      y0 += v * inval(wy, c, f32);
      y1 += v * inval(wy, 200 + c, f32);
    }
    for (int c = lane; c < 300; c += 64) {
      float v = bf2f(Z2[(size_t)row * 300 + c]);
      z0 += v * inval(wz, c, f32);
      z1 += v * inval(wz, 300 + c, f32);
    }
  }
  for (int off = 32; off > 0; off >>= 1) {
    y0 += __shfl_down(y0, off);
    y1 += __shfl_down(y1, off);
    z0 += __shfl_down(z0, off);
    z1 += __shfl_down(z1, off);
  }
  if (lane == 0) {
    float p0 = 0.f, p1 = 0.f;
    if (row < 12497) {
      p0 = (y0 + inval(by, 0, f32)) * (z0 + inval(bz, 0, f32));
      p1 = (y1 + inval(by, 1, f32)) * (z1 + inval(bz, 1, f32));
    }
    bl[g * 2] = p0; bl[g * 2 + 1] = p1;
  }
  __syncthreads();
  if (threadIdx.x == 0) {
    pacc[(size_t)blockIdx.x * 2]     = bl[0] + bl[2] + bl[4] + bl[6];
    pacc[(size_t)blockIdx.x * 2 + 1] = bl[1] + bl[3] + bl[5] + bl[7];
  }
}

__global__ __launch_bounds__(256) void finalize_kernel(
    const float* __restrict__ pacc, int nblk, const int* __restrict__ dflag,
    void* __restrict__ out) {
  const int f32 = *dflag;
  __shared__ float red[2][4];
  int t = threadIdx.x;
  float s0 = 0.f, s1 = 0.f;
  for (int i = t; i < nblk; i += 256) { s0 += pacc[2 * i]; s1 += pacc[2 * i + 1]; }
  for (int off = 32; off; off >>= 1) { s0 += __shfl_down(s0, off); s1 += __shfl_down(s1, off); }
  int w = t >> 6;
  if ((t & 63) == 0) { red[0][w] = s0; red[1][w] = s1; }
  __syncthreads();
  if (t == 0) {
    float a0 = (red[0][0] + red[0][1] + red[0][2] + red[0][3]) / 12497.f;
    float a1 = (red[1][0] + red[1][1] + red[1][2] + red[1][3]) / 12497.f;
    float mx = fmaxf(a0, a1);
    float e0 = expf(a0 - mx), e1 = expf(a1 - mx);
    float s = e0 + e1;
    if (f32) {
      ((float*)out)[0] = e0 / s;
      ((float*)out)[1] = e1 / s;
    } else {
      ((ushort_t*)out)[0] = f2bf(e0 / s);
      ((ushort_t*)out)[1] = f2bf(e1 / s);
    }
  }
}

// ---------------------------------------------------------------- launch
extern "C" void kernel_launch(void* const* d_in, const int* in_sizes, int n_in,
                              void* d_out, int out_size, void* d_ws, size_t ws_size,
                              hipStream_t stream) {
  const void* x        = d_in[0];
  const int*  edge     = (const int*)d_in[1];
  const void* ggnn_w   = d_in[2];
  const void* gru_wih  = d_in[3];
  const void* gru_whh  = d_in[4];
  const void* gru_bih  = d_in[5];
  const void* gru_bhh  = d_in[6];
  const void* conv1_w  = d_in[7];
  const void* conv1_b  = d_in[8];
  const void* conv2_w  = d_in[9];
  const void* conv2_b  = d_in[10];
  const void* conv1c_w = d_in[11];
  const void* conv1c_b = d_in[12];
  const void* conv2c_w = d_in[13];
  const void* conv2c_b = d_in[14];
  const void* bn_g     = d_in[15];
  const void* bn_b     = d_in[16];
  const void* bnc_g    = d_in[17];
  const void* bnc_b    = d_in[18];
  const void* mlpy_w   = d_in[19];
  const void* mlpy_b   = d_in[20];
  const void* mlpz_w   = d_in[21];
  const void* mlpz_b   = d_in[22];
  const int* srcv = edge;
  const int* dstv = edge + NEDGES;

  // ---- workspace layout (aliased; total ~177 MB) ----
  char* p = (char*)d_ws;
  auto alloc = [&](size_t bytes) -> char* {
    char* r = p; p += (bytes + 255) & ~(size_t)255; return r;
  };
  ushort_t* h    = (ushort_t*)alloc(((size_t)NNODES * FOUT + 64) * 2);     // 20 MB
  ushort_t* Ag   = (ushort_t*)alloc(((size_t)NNODES * 400 + 64) * 2);     // 40 MB (cc aliases)
  ushort_t* cc   = Ag;  // cc[N,300] built AFTER GRU loop, Ag then dead
  char*     R    = alloc((size_t)98 * 1000 * 1000);                        // 98 MB arena
  ushort_t* G    = (ushort_t*)R;                  // [N,800] bf16 GRU gates (GRU phase only)
  float*    C1   = (float*)R;                     // 40 MB  (conv phase, sequential)
  float*    C2   = (float*)R;                     // 20 MB
  float*    C1c  = (float*)R;                     // 60 MB
  float*    C2c  = (float*)R;                     // 30 MB
  ushort_t* pooled1 = (ushort_t*)(R + 60000000);  // 10 MB, live while C2 written
  ushort_t* pooledc = (ushort_t*)(R + 70000000);  // 15 MB, live while C2c written
  ushort_t* Y2      = (ushort_t*)(R + 85000000);  //  5 MB
  ushort_t* Z2      = (ushort_t*)(R + 90000000);  //  7.5 MB (ends 97.5 MB)
  ushort_t* BtG  = (ushort_t*)alloc((size_t)8 * 896 * 416 * 2);
  ushort_t* Bt1  = (ushort_t*)alloc((size_t)256 * 800 * 2);
  ushort_t* Bt2  = (ushort_t*)alloc((size_t)256 * 416 * 2);
  ushort_t* Bt1c = (ushort_t*)alloc((size_t)384 * 1216 * 2);
  ushort_t* Bt2c = (ushort_t*)alloc((size_t)384 * 608 * 2);
  ushort_t* gwp  = (ushort_t*)alloc((size_t)1600 * 224 * 2);
  ushort_t* wihp = (ushort_t*)alloc((size_t)640 * 224 * 2);
  float*    Wp   = (float*)alloc((size_t)1600 * 600 * 4);
  int*   csr_src = (int*)alloc((size_t)NEDGES * 4);
  int*   row_ptr = (int*)alloc((size_t)(NNODES + 1) * 4);
  int*   cursor  = (int*)alloc((size_t)NNODES * 4);
  int*   cnt     = (int*)alloc((size_t)NNODES * 4);
  float* pacc    = (float*)alloc((size_t)3125 * 2 * 4);
  float* sb      = (float*)alloc((size_t)3300 * 4);
  float *s1 = sb, *ss1 = sb + 200, *s2 = sb + 400, *ss2 = sb + 600;
  float *sc1 = sb + 800, *ssc1 = sb + 1100, *sc2 = sb + 1400, *ssc2 = sb + 1700;
  int*   dflag = (int*)(sb + 2002);
  float* b1f   = sb + 2010;
  float* b2f   = sb + 2210;
  float* b1cf  = sb + 2410;
  float* b2cf  = sb + 2710;

  size_t required = (size_t)(p - (char*)d_ws);
  if (required > ws_size) {
    sentinel_kernel<<<1, 64, 0, stream>>>((ushort_t*)d_out);
    return;
  }

  probe_kernel<<<1, 64, 0, stream>>>(x, dflag);
  zero_kernel<<<(NNODES + 255) / 256, 256, 0, stream>>>(cnt, NNODES);
  zero_kernel<<<(2000 + 255) / 256, 256, 0, stream>>>((int*)sb, 2000);
  hinit_kernel<<<(NNODES * FOUT + 255) / 256, 256, 0, stream>>>(x, dflag, h);

  // wp = ggnn_w @ wih^T as one MFMA GEMM: A=gwp[1600][224], Bt=wihp[640][224]
  pada_kernel<<<(1600 * 224 + 255) / 256, 256, 0, stream>>>(ggnn_w, dflag, gwp, 200, 224, 1600, 1600 * 224);
  pada_kernel<<<(640 * 224 + 255) / 256, 256, 0, stream>>>(gru_wih, dflag, wihp, 200, 224, 600, 640 * 224);
  gemm128<false><<<dim3(13, 5), 256, 0, stream>>>(gwp, 224, wihp, Wp, 600, 1600, 600, 224, nullptr);

  btgru_kernel<<<(NSTEPS * 896 * 416 + 255) / 256, 256, 0, stream>>>(Wp, gru_whh, dflag, BtG);
  btconv_kernel<<<(256 * 800 + 255) / 256, 256, 0, stream>>>(conv1_w, dflag, Bt1, 200, 4, 800, 200, 256 * 800);
  btconv_kernel<<<(256 * 416 + 255) / 256, 256, 0, stream>>>(conv2_w, dflag, Bt2, 200, 2, 416, 200, 256 * 416);
  btconv_kernel<<<(384 * 1216 + 255) / 256, 256, 0, stream>>>(conv1c_w, dflag, Bt1c, 300, 4, 1216, 300, 384 * 1216);
  btconv_kernel<<<(384 * 608 + 255) / 256, 256, 0, stream>>>(conv2c_w, dflag, Bt2c, 300, 2, 608, 300, 384 * 608);
  bias_kernel<<<1, 256, 0, stream>>>(conv1_b, dflag, b1f, 200);
  bias_kernel<<<1, 256, 0, stream>>>(conv2_b, dflag, b2f, 200);
  bias_kernel<<<2, 256, 0, stream>>>(conv1c_b, dflag, b1cf, 300);
  bias_kernel<<<2, 256, 0, stream>>>(conv2c_b, dflag, b2cf, 300);

  hist_kernel<<<(NEDGES + 255) / 256, 256, 0, stream>>>(dstv, cnt);
  scan_kernel<<<1, 1024, 0, stream>>>(cnt, row_ptr, cursor);
  fill_kernel<<<(NEDGES + 255) / 256, 256, 0, stream>>>(srcv, dstv, cursor, csr_src);

  for (int l = 0; l < NSTEPS; l++) {
    gather_kernel<<<(NNODES + 3) / 4, 256, 0, stream>>>(row_ptr, csr_src, h, Ag);
    gemm128<true><<<dim3(391, 7), 256, 0, stream>>>(Ag, 400, BtG + (size_t)l * 896 * 416,
                                                    G, 800, NNODES, 800, 416, nullptr);
    gru_kernel<<<(NNODES * FOUT + 255) / 256, 256, 0, stream>>>(G, gru_bih, gru_bhh, dflag, h);
  }
  ccat_kernel<<<(NNODES * FCAT + 255) / 256, 256, 0, stream>>>(h, x, dflag, cc);

  // branch y
  gemm128<false><<<dim3(391, 2), 256, 0, stream>>>(h, 200, Bt1, C1, 200, 49997, 200, 800, b1f);
  stats_kernel<<<(49997 + 63) / 64, 256, 0, stream>>>(C1, 49997, 200, s1, ss1);
  bnpool_kernel<<<(24997 * 200 + 255) / 256, 256, 0, stream>>>(C1, 49997, 200, 4, 2, 24997,
                                                               s1, ss1, bn_g, bn_b, dflag, pooled1);
  gemm128<false><<<dim3(196, 2), 256, 0, stream>>>(pooled1, 200, Bt2, C2, 200, 24996, 200, 416, b2f);
  stats_kernel<<<(24996 + 63) / 64, 256, 0, stream>>>(C2, 24996, 200, s2, ss2);
  bnpool_kernel<<<(12497 * 200 + 255) / 256, 256, 0, stream>>>(C2, 24996, 200, 3, 2, 12497,
                                                               s2, ss2, bn_g, bn_b, dflag, Y2);
  // branch z
  gemm128<false><<<dim3(391, 3), 256, 0, stream>>>(cc, 300, Bt1c, C1c, 300, 49997, 300, 1216, b1cf);
  stats_kernel<<<(49997 + 63) / 64, 256, 0, stream>>>(C1c, 49997, 300, sc1, ssc1);
  bnpool_kernel<<<(24997 * 300 + 255) / 256, 256, 0, stream>>>(C1c, 49997, 300, 4, 2, 24997,
                                                               sc1, ssc1, bnc_g, bnc_b, dflag, pooledc);
  gemm128<false><<<dim3(196, 3), 256, 0, stream>>>(pooledc, 300, Bt2c, C2c, 300, 24996, 300, 608, b2cf);
  stats_kernel<<<(24996 + 63) / 64, 256, 0, stream>>>(C2c, 24996, 300, sc2, ssc2);
  bnpool_kernel<<<(12497 * 300 + 255) / 256, 256, 0, stream>>>(C2c, 24996, 300, 3, 2, 12497,
                                                               sc2, ssc2, bnc_g, bnc_b, dflag, Z2);

  final_kernel<<<3125, 256, 0, stream>>>(Y2, Z2, mlpy_w, mlpy_b, mlpz_w, mlpz_b, dflag, pacc);
  finalize_kernel<<<1, 256, 0, stream>>>(pacc, 3125, dflag, d_out);
}